// Round 8
// baseline (726.821 us; speedup 1.0000x reference)
//
#include <hip/hip_runtime.h>
#include <hip/hip_bf16.h>
#include <stdint.h>

using bf16 = __hip_bfloat16;
typedef __attribute__((ext_vector_type(8))) short bf16x8;
typedef __attribute__((ext_vector_type(4))) float f32x4;
typedef __attribute__((ext_vector_type(2))) int i32x2;

#define SCALE 0.125f

__device__ __forceinline__ float b2f(bf16 x) { return __bfloat162float(x); }
__device__ __forceinline__ bf16 f2b(float x) { return __float2bfloat16(x); }

__device__ __forceinline__ void gll16(const void* g, void* l) {
  __builtin_amdgcn_global_load_lds((const __attribute__((address_space(1))) void*)g,
                                   (__attribute__((address_space(3))) void*)l, 16, 0, 0);
}

__device__ __forceinline__ bf16x8 cat64(i32x2 a, i32x2 b) {
  int4 v; v.x = a.x; v.y = a.y; v.z = b.x; v.w = b.y;
  return *(bf16x8*)&v;
}

// ---------------- fp32 -> bf16 conversion ----------------
__global__ __launch_bounds__(256) void cvt_kernel(const float* __restrict__ in, bf16* __restrict__ out, int n4) {
  int i = blockIdx.x * 256 + threadIdx.x;
  if (i >= n4) return;
  float4 v = ((const float4*)in)[i];
  alignas(8) bf16 o[4];
  o[0] = f2b(v.x); o[1] = f2b(v.y); o[2] = f2b(v.z); o[3] = f2b(v.w);
  ((uint2*)out)[i] = *(const uint2*)o;
}

// ---------------- GEMM: C[m,n] = sum_k A[m,k] * B[n,k]  (A:[M,K], B:[N,K] row-major bf16)
template<int STORE_BF16>
__global__ __launch_bounds__(256) void gemm_bt(const bf16* __restrict__ A, const bf16* __restrict__ B,
                                               void* __restrict__ C, int M, int N, int K) {
  __shared__ bf16 As[128][72];
  __shared__ bf16 Bs[128][72];
  const int tid = threadIdx.x;
  const int lane = tid & 63;
  const int w = tid >> 6, wr = w >> 1, wc = w & 1;
  const int m0 = blockIdx.y * 128, n0 = blockIdx.x * 128;
  const int lr = lane & 15, lg = lane >> 4;
  f32x4 acc[4][4] = {};
  for (int k0 = 0; k0 < K; k0 += 64) {
    __syncthreads();
#pragma unroll
    for (int i = 0; i < 4; ++i) {
      int c = tid + i * 256;           // 0..1023 chunks of 8 bf16
      int row = c >> 3, seg = c & 7;
      *(int4*)&As[row][seg * 8] = *(const int4*)&A[(size_t)(m0 + row) * K + k0 + seg * 8];
      *(int4*)&Bs[row][seg * 8] = *(const int4*)&B[(size_t)(n0 + row) * K + k0 + seg * 8];
    }
    __syncthreads();
#pragma unroll
    for (int kk = 0; kk < 2; ++kk) {
      bf16x8 af[4], bfv[4];
#pragma unroll
      for (int m = 0; m < 4; ++m) af[m] = *(const bf16x8*)&As[wr * 64 + m * 16 + lr][kk * 32 + lg * 8];
#pragma unroll
      for (int n = 0; n < 4; ++n) bfv[n] = *(const bf16x8*)&Bs[wc * 64 + n * 16 + lr][kk * 32 + lg * 8];
#pragma unroll
      for (int m = 0; m < 4; ++m)
#pragma unroll
        for (int n = 0; n < 4; ++n)
          acc[m][n] = __builtin_amdgcn_mfma_f32_16x16x32_bf16(af[m], bfv[n], acc[m][n], 0, 0, 0);
    }
  }
#pragma unroll
  for (int m = 0; m < 4; ++m)
#pragma unroll
    for (int n = 0; n < 4; ++n)
#pragma unroll
      for (int r = 0; r < 4; ++r) {
        int row = m0 + wr * 64 + m * 16 + lg * 4 + r;
        int col = n0 + wc * 64 + n * 16 + lr;
        if (STORE_BF16) ((bf16*)C)[(size_t)row * N + col] = f2b(acc[m][n][r]);
        else            ((float*)C)[(size_t)row * N + col] = acc[m][n][r];
      }
}

// ---------------- fused flash attention with in-kernel rel-shift BD
// u = j - i:  u<=0 -> BD = qr_i . rk[u+2047]; u==1 -> 0; u>=2 -> BD = qr_{i+1} . rk[u-2]
// Un-normalized streaming softmax (scores bounded; exp(s) safe in fp32/bf16):
// no per-iteration cross-lane reductions; single shuffle reduce of row-sums at end.
// K read directly from global (L2-resident); V double-buffered via global_load_lds;
// Tp/Ps are per-wave-private rows; single barrier per iteration guards V only.
__global__ __launch_bounds__(256) void flash_kernel(const bf16* __restrict__ wh, const bf16* __restrict__ rk,
                                                    const float* __restrict__ rwb, const float* __restrict__ rrb,
                                                    bf16* __restrict__ av) {
  const int bn = blockIdx.y;
  const int b = bn >> 4, n = bn & 15;
  const int q0 = blockIdx.x * 64;
  const int tid = threadIdx.x, lane = tid & 63, w = tid >> 6;
  const int lr = lane & 15, lg = lane >> 4;
  __shared__ bf16 VtA[2 * 4096];   // subtiled: elem p = dblk*1024 + jblk*64 + (j&3)*16 + (d&15)
  __shared__ bf16 Ps[64][64];      // col swizzle: col' = col ^ ((row&7)<<3); per-wave-private rows
  __shared__ bf16 Tp[64][128];     // rolling BD panel; per-wave-private rows

  // --- Q fragments (AC path, +r_w_bias) and Qr fragments (BD path, +r_r_bias, rows +0/+1)
  bf16x8 qf[2], qrf[2][2];
#pragma unroll
  for (int kk = 0; kk < 2; ++kk) {
    {
      int row = q0 + w * 16 + lr;
      int4 raw = *(const int4*)&wh[((size_t)row * 4 + b) * 3072 + n * 64 + kk * 32 + lg * 8];
      const bf16* rp = (const bf16*)&raw;
      alignas(16) bf16 ov[8];
#pragma unroll
      for (int e = 0; e < 8; ++e) ov[e] = f2b((b2f(rp[e]) + rwb[n * 64 + kk * 32 + lg * 8 + e]) * SCALE);
      qf[kk] = *(const bf16x8*)ov;
    }
#pragma unroll
    for (int ao = 0; ao < 2; ++ao) {
      int row = q0 + ao + w * 16 + lr; if (row > 2047) row = 2047;
      int4 raw = *(const int4*)&wh[((size_t)row * 4 + b) * 3072 + n * 64 + kk * 32 + lg * 8];
      const bf16* rp = (const bf16*)&raw;
      alignas(16) bf16 ov[8];
#pragma unroll
      for (int e = 0; e < 8; ++e) ov[e] = f2b((b2f(rp[e]) + rrb[n * 64 + kk * 32 + lg * 8 + e]) * SCALE);
      qrf[ao][kk] = *(const bf16x8*)ov;
    }
  }

  // panel coordinates for iteration u (u = j0/64)
  auto coords = [&](int u, int& pbase, int& sub) {
    int tt = 64 * u - q0;
    if (tt <= -64) { pbase = tt + 2048; sub = 0; } else { pbase = tt; sub = 2; }
  };

  // panel GEMM with direct global loads -> Tp (per-wave rows only, no barrier needed)
  auto panel_direct = [&](int pbase, int sub) {
    const int aidx = sub ? 1 : 0;
#pragma unroll
    for (int nt = 0; nt < 4; ++nt) {
      int c = pbase + nt * 16 + lr - sub;
      c = c < 0 ? 0 : (c > 2047 ? 2047 : c);
      f32x4 pacc = {};
      bf16x8 b0 = *(const bf16x8*)&rk[(size_t)c * 1024 + n * 64 + lg * 8];
      bf16x8 b1 = *(const bf16x8*)&rk[(size_t)c * 1024 + n * 64 + 32 + lg * 8];
      pacc = __builtin_amdgcn_mfma_f32_16x16x32_bf16(qrf[aidx][0], b0, pacc, 0, 0, 0);
      pacc = __builtin_amdgcn_mfma_f32_16x16x32_bf16(qrf[aidx][1], b1, pacc, 0, 0, 0);
      int cm = (pbase + nt * 16 + lr) & 127;
#pragma unroll
      for (int r = 0; r < 4; ++r) Tp[w * 16 + lg * 4 + r][cm] = f2b(pacc[r]);
    }
  };

  // --- V staging via global_load_lds into subtiled layout
  auto stage_v = [&](int j0, int bufi) {
#pragma unroll
    for (int i = 0; i < 2; ++i) {
      int c = tid + i * 256;
      int jj = ((c >> 3) & 15) * 4 + ((c >> 1) & 3);
      int d0 = (c >> 7) * 16 + (c & 1) * 8;
      gll16(&wh[((size_t)(j0 + jj) * 4 + b) * 3072 + 2048 + n * 64 + d0],
            &VtA[bufi * 4096 + (w * 64 + i * 256) * 8]);
    }
  };

  // --- prologue: panels (back-window + iter-0 window), stage V tile 0
  panel_direct(1984 - q0, 0);
  { int pb, sb; coords(0, pb, sb); panel_direct(pb, sb); }
  stage_v(0, 0);

  // per-lane tr-read base: column select dlow=lr (+2*lr bytes), jblk pair = kk*8+2*lg (lg*256 bytes)
  const unsigned vtb = (unsigned)(uintptr_t)(__attribute__((address_space(3))) bf16*)VtA
                       + (unsigned)(lg * 256 + lr * 2);
  const bf16* kbase = wh + (size_t)b * 3072 + 1024 + n * 64;

  float lrow[4] = {0.f, 0.f, 0.f, 0.f};
  f32x4 oacc[4] = {};

  __syncthreads();   // V tile 0 ready (vmcnt drained by barrier)

  int buf = 0;
  for (int u = 0; u < 32; ++u) {
    const int j0 = u * 64;
    if (u < 31) stage_v(j0 + 64, buf ^ 1);   // in flight across this iteration's compute

    // BD gather from rolling panel into temporaries (covers K-load latency)
    float bd[4][4];
#pragma unroll
    for (int f = 0; f < 4; ++f) {
      int jj = j0 + f * 16 + lr;
#pragma unroll
      for (int r = 0; r < 4; ++r) {
        int i = q0 + w * 16 + lg * 4 + r;
        int uu = jj - i;
        if (uu != 1) {
          int cm = (uu >= 2 ? uu : uu - 1) & 127;   // u+2047 == u-1 (mod 128)
          bd[f][r] = b2f(Tp[w * 16 + lg * 4 + r][cm]);
        } else bd[f][r] = 0.f;
      }
    }
    // AC: S = qf . K^T with K fragments loaded directly from global (L2-resident)
    f32x4 s[4] = {};
#pragma unroll
    for (int kk = 0; kk < 2; ++kk)
#pragma unroll
      for (int f = 0; f < 4; ++f) {
        bf16x8 kf = *(const bf16x8*)&kbase[(size_t)(j0 + f * 16 + lr) * 12288 + kk * 32 + lg * 8];
        s[f] = __builtin_amdgcn_mfma_f32_16x16x32_bf16(qf[kk], kf, s[f], 0, 0, 0);
      }
    // P = exp(AC + BD)  (no max subtraction: scores bounded, shift-invariant softmax)
#pragma unroll
    for (int f = 0; f < 4; ++f)
#pragma unroll
      for (int r = 0; r < 4; ++r) {
        float p = __expf(s[f][r] + bd[f][r]);
        s[f][r] = p;
        lrow[r] += p;
      }
    // P -> LDS (swizzled, per-wave rows)
#pragma unroll
    for (int f = 0; f < 4; ++f)
#pragma unroll
      for (int r = 0; r < 4; ++r) {
        int row = w * 16 + lg * 4 + r;
        Ps[row][(f * 16 + lr) ^ ((row & 7) << 3)] = f2b(s[f][r]);
      }
    // PV: B-fragments via hardware transpose reads from subtiled V
    {
      unsigned va = vtb + (unsigned)(buf << 13);
      i32x2 t0, t1, t2, t3, t4, t5, t6, t7;
      bf16x8 pf;
#define TRRD(d_, o_) asm volatile("ds_read_b64_tr_b16 %0, %1 offset:" o_ : "=v"(d_) : "v"(va))
      // kk = 0
      pf = *(const bf16x8*)&Ps[w * 16 + lr][((0 * 4 + lg) ^ (lr & 7)) * 8];
      TRRD(t0, "0");    TRRD(t1, "128");
      TRRD(t2, "2048"); TRRD(t3, "2176");
      TRRD(t4, "4096"); TRRD(t5, "4224");
      TRRD(t6, "6144"); TRRD(t7, "6272");
      asm volatile("s_waitcnt lgkmcnt(0)" ::: "memory");
      __builtin_amdgcn_sched_barrier(0);
      oacc[0] = __builtin_amdgcn_mfma_f32_16x16x32_bf16(pf, cat64(t0, t1), oacc[0], 0, 0, 0);
      oacc[1] = __builtin_amdgcn_mfma_f32_16x16x32_bf16(pf, cat64(t2, t3), oacc[1], 0, 0, 0);
      oacc[2] = __builtin_amdgcn_mfma_f32_16x16x32_bf16(pf, cat64(t4, t5), oacc[2], 0, 0, 0);
      oacc[3] = __builtin_amdgcn_mfma_f32_16x16x32_bf16(pf, cat64(t6, t7), oacc[3], 0, 0, 0);
      // kk = 1
      pf = *(const bf16x8*)&Ps[w * 16 + lr][((1 * 4 + lg) ^ (lr & 7)) * 8];
      TRRD(t0, "1024"); TRRD(t1, "1152");
      TRRD(t2, "3072"); TRRD(t3, "3200");
      TRRD(t4, "5120"); TRRD(t5, "5248");
      TRRD(t6, "7168"); TRRD(t7, "7296");
      asm volatile("s_waitcnt lgkmcnt(0)" ::: "memory");
      __builtin_amdgcn_sched_barrier(0);
      oacc[0] = __builtin_amdgcn_mfma_f32_16x16x32_bf16(pf, cat64(t0, t1), oacc[0], 0, 0, 0);
      oacc[1] = __builtin_amdgcn_mfma_f32_16x16x32_bf16(pf, cat64(t2, t3), oacc[1], 0, 0, 0);
      oacc[2] = __builtin_amdgcn_mfma_f32_16x16x32_bf16(pf, cat64(t4, t5), oacc[2], 0, 0, 0);
      oacc[3] = __builtin_amdgcn_mfma_f32_16x16x32_bf16(pf, cat64(t6, t7), oacc[3], 0, 0, 0);
#undef TRRD
    }
    // next iteration's BD panel (direct loads; rk hot in L2)
    if (u < 31) {
      int pb, sb; coords(u + 1, pb, sb);
      panel_direct(pb, sb);
    }
    __syncthreads();   // staging of u+1 complete, all PV reads of buf done
    buf ^= 1;
  }
  // final row-sum reduce across the 16-lane group (once, not per iteration)
#pragma unroll
  for (int r = 0; r < 4; ++r)
#pragma unroll
    for (int msk = 1; msk <= 8; msk <<= 1) lrow[r] += __shfl_xor(lrow[r], msk);
#pragma unroll
  for (int df = 0; df < 4; ++df)
#pragma unroll
    for (int r = 0; r < 4; ++r) {
      int i = q0 + w * 16 + lg * 4 + r;
      av[((size_t)i * 4 + b) * 1024 + n * 64 + df * 16 + lr] = f2b(oacc[df][r] / lrow[r]);
    }
}

// ---------------- residual + LayerNorm ----------------
__global__ __launch_bounds__(256) void ln_kernel(const float* __restrict__ w, const float* __restrict__ ao,
                                                 const float* __restrict__ g, const float* __restrict__ bb,
                                                 float* __restrict__ out) {
  const int row = blockIdx.x;
  const int t = threadIdx.x;
  const float4 wv = ((const float4*)(w + (size_t)row * 1024))[t];
  const float4 av = ((const float4*)(ao + (size_t)row * 1024))[t];
  float x0 = wv.x + av.x, x1 = wv.y + av.y, x2 = wv.z + av.z, x3 = wv.w + av.w;
  float s1 = x0 + x1 + x2 + x3;
  float s2 = x0 * x0 + x1 * x1 + x2 * x2 + x3 * x3;
#pragma unroll
  for (int m = 1; m <= 32; m <<= 1) { s1 += __shfl_xor(s1, m); s2 += __shfl_xor(s2, m); }
  __shared__ float red[8];
  const int lane = t & 63, wv2 = t >> 6;
  if (lane == 0) { red[wv2] = s1; red[4 + wv2] = s2; }
  __syncthreads();
  s1 = red[0] + red[1] + red[2] + red[3];
  s2 = red[4] + red[5] + red[6] + red[7];
  const float mu = s1 * (1.f / 1024.f);
  const float var = s2 * (1.f / 1024.f) - mu * mu;
  const float rr = rsqrtf(var + 1e-5f);
  const float4 gv = ((const float4*)g)[t];
  const float4 bv = ((const float4*)bb)[t];
  float4 o;
  o.x = (x0 - mu) * rr * gv.x + bv.x;
  o.y = (x1 - mu) * rr * gv.y + bv.y;
  o.z = (x2 - mu) * rr * gv.z + bv.z;
  o.w = (x3 - mu) * rr * gv.w + bv.w;
  ((float4*)(out + (size_t)row * 1024))[t] = o;
}

extern "C" void kernel_launch(void* const* d_in, const int* in_sizes, int n_in,
                              void* d_out, int out_size, void* d_ws, size_t ws_size,
                              hipStream_t stream) {
  const float* w    = (const float*)d_in[0];
  const float* r    = (const float*)d_in[1];
  const float* qkvw = (const float*)d_in[2];
  const float* rnw  = (const float*)d_in[3];
  const float* ow   = (const float*)d_in[4];
  const float* rwb  = (const float*)d_in[5];
  const float* rrb  = (const float*)d_in[6];
  const float* lng  = (const float*)d_in[7];
  const float* lnb  = (const float*)d_in[8];
  float* out = (float*)d_out;

  char* ws = (char*)d_ws;
  size_t off = 0;
  auto alloc = [&](size_t bytes) -> char* {
    char* p = ws + off; off += (bytes + 255) & ~((size_t)255); return p;
  };
  bf16*  wb  = (bf16*)alloc((size_t)8192 * 1024 * 2);
  bf16*  qb  = (bf16*)alloc((size_t)3072 * 1024 * 2);
  bf16*  rb  = (bf16*)alloc((size_t)2048 * 1024 * 2);
  bf16*  rnb = (bf16*)alloc((size_t)1024 * 1024 * 2);
  bf16*  owb = (bf16*)alloc((size_t)1024 * 1024 * 2);
  bf16*  wh  = (bf16*)alloc((size_t)8192 * 3072 * 2);
  bf16*  rkb = (bf16*)alloc((size_t)2048 * 1024 * 2);
  bf16*  avb = (bf16*)alloc((size_t)8192 * 1024 * 2);
  float* ao  = (float*)alloc((size_t)8192 * 1024 * 4);

  auto cvt = [&](const float* in, bf16* o, size_t nelem) {
    int n4 = (int)(nelem / 4);
    cvt_kernel<<<dim3((n4 + 255) / 256), dim3(256), 0, stream>>>(in, o, n4);
  };
  cvt(w, wb, (size_t)8192 * 1024);
  cvt(qkvw, qb, (size_t)3072 * 1024);
  cvt(r, rb, (size_t)2048 * 1024);
  cvt(rnw, rnb, (size_t)1024 * 1024);
  cvt(ow, owb, (size_t)1024 * 1024);

  gemm_bt<1><<<dim3(3072 / 128, 8192 / 128), dim3(256), 0, stream>>>(wb, qb, wh, 8192, 3072, 1024);
  gemm_bt<1><<<dim3(1024 / 128, 2048 / 128), dim3(256), 0, stream>>>(rb, rnb, rkb, 2048, 1024, 1024);

  flash_kernel<<<dim3(32, 64), dim3(256), 0, stream>>>(wh, rkb, rwb, rrb, avb);

  gemm_bt<0><<<dim3(1024 / 128, 8192 / 128), dim3(256), 0, stream>>>(avb, owb, ao, 8192, 1024, 1024);
  ln_kernel<<<dim3(8192), dim3(256), 0, stream>>>(w, ao, lng, lnb, out);
}

// Round 9
// 719.453 us; speedup vs baseline: 1.0102x; 1.0102x over previous
//
#include <hip/hip_runtime.h>
#include <hip/hip_bf16.h>
#include <stdint.h>

using bf16 = __hip_bfloat16;
typedef __attribute__((ext_vector_type(8))) short bf16x8;
typedef __attribute__((ext_vector_type(4))) float f32x4;
typedef __attribute__((ext_vector_type(2))) int i32x2;

#define SCALE 0.125f

__device__ __forceinline__ float b2f(bf16 x) { return __bfloat162float(x); }
__device__ __forceinline__ bf16 f2b(float x) { return __float2bfloat16(x); }

__device__ __forceinline__ void gll16(const void* g, void* l) {
  __builtin_amdgcn_global_load_lds((const __attribute__((address_space(1))) void*)g,
                                   (__attribute__((address_space(3))) void*)l, 16, 0, 0);
}

__device__ __forceinline__ bf16x8 cat64(i32x2 a, i32x2 b) {
  int4 v; v.x = a.x; v.y = a.y; v.z = b.x; v.w = b.y;
  return *(bf16x8*)&v;
}

// ---------------- fp32 -> bf16 conversion ----------------
__global__ __launch_bounds__(256) void cvt_kernel(const float* __restrict__ in, bf16* __restrict__ out, int n4) {
  int i = blockIdx.x * 256 + threadIdx.x;
  if (i >= n4) return;
  float4 v = ((const float4*)in)[i];
  alignas(8) bf16 o[4];
  o[0] = f2b(v.x); o[1] = f2b(v.y); o[2] = f2b(v.z); o[3] = f2b(v.w);
  ((uint2*)out)[i] = *(const uint2*)o;
}

// ---------------- GEMM: C[m,n] = sum_k A[m,k] * B[n,k]  (A:[M,K], B:[N,K] row-major bf16)
template<int STORE_BF16>
__global__ __launch_bounds__(256) void gemm_bt(const bf16* __restrict__ A, const bf16* __restrict__ B,
                                               void* __restrict__ C, int M, int N, int K) {
  __shared__ bf16 As[128][72];
  __shared__ bf16 Bs[128][72];
  const int tid = threadIdx.x;
  const int lane = tid & 63;
  const int w = tid >> 6, wr = w >> 1, wc = w & 1;
  const int m0 = blockIdx.y * 128, n0 = blockIdx.x * 128;
  const int lr = lane & 15, lg = lane >> 4;
  f32x4 acc[4][4] = {};
  for (int k0 = 0; k0 < K; k0 += 64) {
    __syncthreads();
#pragma unroll
    for (int i = 0; i < 4; ++i) {
      int c = tid + i * 256;           // 0..1023 chunks of 8 bf16
      int row = c >> 3, seg = c & 7;
      *(int4*)&As[row][seg * 8] = *(const int4*)&A[(size_t)(m0 + row) * K + k0 + seg * 8];
      *(int4*)&Bs[row][seg * 8] = *(const int4*)&B[(size_t)(n0 + row) * K + k0 + seg * 8];
    }
    __syncthreads();
#pragma unroll
    for (int kk = 0; kk < 2; ++kk) {
      bf16x8 af[4], bfv[4];
#pragma unroll
      for (int m = 0; m < 4; ++m) af[m] = *(const bf16x8*)&As[wr * 64 + m * 16 + lr][kk * 32 + lg * 8];
#pragma unroll
      for (int n = 0; n < 4; ++n) bfv[n] = *(const bf16x8*)&Bs[wc * 64 + n * 16 + lr][kk * 32 + lg * 8];
#pragma unroll
      for (int m = 0; m < 4; ++m)
#pragma unroll
        for (int n = 0; n < 4; ++n)
          acc[m][n] = __builtin_amdgcn_mfma_f32_16x16x32_bf16(af[m], bfv[n], acc[m][n], 0, 0, 0);
    }
  }
#pragma unroll
  for (int m = 0; m < 4; ++m)
#pragma unroll
    for (int n = 0; n < 4; ++n)
#pragma unroll
      for (int r = 0; r < 4; ++r) {
        int row = m0 + wr * 64 + m * 16 + lg * 4 + r;
        int col = n0 + wc * 64 + n * 16 + lr;
        if (STORE_BF16) ((bf16*)C)[(size_t)row * N + col] = f2b(acc[m][n][r]);
        else            ((float*)C)[(size_t)row * N + col] = acc[m][n][r];
      }
}

// ---------------- fused flash attention with in-kernel rel-shift BD
// u = j - i:  u<=0 -> BD = qr_i . rk[u+2047]; u==1 -> 0; u>=2 -> BD = qr_{i+1} . rk[u-2]
// Un-normalized streaming softmax; K from global (L2-resident via XCD swizzle);
// V dbuf via global_load_lds; Ps halved ([64][32], reused per kk); setprio on MFMA clusters.
__global__ __launch_bounds__(256) void flash_kernel(const bf16* __restrict__ wh, const bf16* __restrict__ rk,
                                                    const float* __restrict__ rwb, const float* __restrict__ rrb,
                                                    bf16* __restrict__ av) {
  // XCD-aware decode: 32 q-blocks sharing one (b,n) land on one XCD
  const int hid = blockIdx.x;
  const int xcd = hid & 7;
  const int idx = hid >> 3;
  const int bn = xcd + 8 * (idx >> 5);
  const int q0 = (idx & 31) * 64;
  const int b = bn >> 4, n = bn & 15;
  const int tid = threadIdx.x, lane = tid & 63, w = tid >> 6;
  const int lr = lane & 15, lg = lane >> 4;
  __shared__ bf16 VtA[2 * 4096];   // subtiled: elem p = dblk*1024 + jblk*64 + (j&3)*16 + (d&15)
  __shared__ bf16 Ps[64][32];      // kk-half reuse; col' = col32 ^ (writer_lg<<3); per-wave rows
  __shared__ bf16 Tp[64][128];     // rolling BD panel; per-wave-private rows

  // --- Q fragments (AC path, +r_w_bias) and Qr fragments (BD path, +r_r_bias, rows +0/+1)
  bf16x8 qf[2], qrf[2][2];
#pragma unroll
  for (int kk = 0; kk < 2; ++kk) {
    {
      int row = q0 + w * 16 + lr;
      int4 raw = *(const int4*)&wh[((size_t)row * 4 + b) * 3072 + n * 64 + kk * 32 + lg * 8];
      const bf16* rp = (const bf16*)&raw;
      alignas(16) bf16 ov[8];
#pragma unroll
      for (int e = 0; e < 8; ++e) ov[e] = f2b((b2f(rp[e]) + rwb[n * 64 + kk * 32 + lg * 8 + e]) * SCALE);
      qf[kk] = *(const bf16x8*)ov;
    }
#pragma unroll
    for (int ao = 0; ao < 2; ++ao) {
      int row = q0 + ao + w * 16 + lr; if (row > 2047) row = 2047;
      int4 raw = *(const int4*)&wh[((size_t)row * 4 + b) * 3072 + n * 64 + kk * 32 + lg * 8];
      const bf16* rp = (const bf16*)&raw;
      alignas(16) bf16 ov[8];
#pragma unroll
      for (int e = 0; e < 8; ++e) ov[e] = f2b((b2f(rp[e]) + rrb[n * 64 + kk * 32 + lg * 8 + e]) * SCALE);
      qrf[ao][kk] = *(const bf16x8*)ov;
    }
  }

  // panel coordinates for iteration u (u = j0/64)
  auto coords = [&](int u, int& pbase, int& sub) {
    int tt = 64 * u - q0;
    if (tt <= -64) { pbase = tt + 2048; sub = 0; } else { pbase = tt; sub = 2; }
  };

  // panel GEMM with direct global loads -> Tp (per-wave rows only, no barrier needed)
  auto panel_direct = [&](int pbase, int sub) {
    const int aidx = sub ? 1 : 0;
#pragma unroll
    for (int nt = 0; nt < 4; ++nt) {
      int c = pbase + nt * 16 + lr - sub;
      c = c < 0 ? 0 : (c > 2047 ? 2047 : c);
      f32x4 pacc = {};
      bf16x8 b0 = *(const bf16x8*)&rk[(size_t)c * 1024 + n * 64 + lg * 8];
      bf16x8 b1 = *(const bf16x8*)&rk[(size_t)c * 1024 + n * 64 + 32 + lg * 8];
      __builtin_amdgcn_s_setprio(1);
      pacc = __builtin_amdgcn_mfma_f32_16x16x32_bf16(qrf[aidx][0], b0, pacc, 0, 0, 0);
      pacc = __builtin_amdgcn_mfma_f32_16x16x32_bf16(qrf[aidx][1], b1, pacc, 0, 0, 0);
      __builtin_amdgcn_s_setprio(0);
      int cm = (pbase + nt * 16 + lr) & 127;
#pragma unroll
      for (int r = 0; r < 4; ++r) Tp[w * 16 + lg * 4 + r][cm] = f2b(pacc[r]);
    }
  };

  // --- V staging via global_load_lds into subtiled layout
  auto stage_v = [&](int j0, int bufi) {
#pragma unroll
    for (int i = 0; i < 2; ++i) {
      int c = tid + i * 256;
      int jj = ((c >> 3) & 15) * 4 + ((c >> 1) & 3);
      int d0 = (c >> 7) * 16 + (c & 1) * 8;
      gll16(&wh[((size_t)(j0 + jj) * 4 + b) * 3072 + 2048 + n * 64 + d0],
            &VtA[bufi * 4096 + (w * 64 + i * 256) * 8]);
    }
  };

  // --- prologue: panels (back-window + iter-0 window), stage V tile 0
  panel_direct(1984 - q0, 0);
  { int pb, sb; coords(0, pb, sb); panel_direct(pb, sb); }
  stage_v(0, 0);

  // per-lane tr-read base: column select dlow=lr (+2*lr bytes), jblk pair = kk*8+2*lg (lg*256 bytes)
  const unsigned vtb = (unsigned)(uintptr_t)(__attribute__((address_space(3))) bf16*)VtA
                       + (unsigned)(lg * 256 + lr * 2);
  const bf16* kbase = wh + (size_t)b * 3072 + 1024 + n * 64;

  float lrow[4] = {0.f, 0.f, 0.f, 0.f};
  f32x4 oacc[4] = {};

  __syncthreads();   // V tile 0 ready (vmcnt drained by barrier)

  int buf = 0;
  for (int u = 0; u < 32; ++u) {
    const int j0 = u * 64;
    if (u < 31) stage_v(j0 + 64, buf ^ 1);   // in flight across this iteration's compute

    // BD gather from rolling panel into temporaries (covers K-load latency)
    float bd[4][4];
#pragma unroll
    for (int f = 0; f < 4; ++f) {
      int jj = j0 + f * 16 + lr;
#pragma unroll
      for (int r = 0; r < 4; ++r) {
        int i = q0 + w * 16 + lg * 4 + r;
        int uu = jj - i;
        if (uu != 1) {
          int cm = (uu >= 2 ? uu : uu - 1) & 127;   // u+2047 == u-1 (mod 128)
          bd[f][r] = b2f(Tp[w * 16 + lg * 4 + r][cm]);
        } else bd[f][r] = 0.f;
      }
    }
    // AC: S = qf . K^T with K fragments loaded directly from global (L2-resident)
    f32x4 s[4] = {};
#pragma unroll
    for (int kk = 0; kk < 2; ++kk)
#pragma unroll
      for (int f = 0; f < 4; ++f) {
        bf16x8 kf = *(const bf16x8*)&kbase[(size_t)(j0 + f * 16 + lr) * 12288 + kk * 32 + lg * 8];
        __builtin_amdgcn_s_setprio(1);
        s[f] = __builtin_amdgcn_mfma_f32_16x16x32_bf16(qf[kk], kf, s[f], 0, 0, 0);
        __builtin_amdgcn_s_setprio(0);
      }
    // P = exp(AC + BD)  (no max subtraction: scores bounded, shift-invariant softmax)
#pragma unroll
    for (int f = 0; f < 4; ++f)
#pragma unroll
      for (int r = 0; r < 4; ++r) {
        float p = __expf(s[f][r] + bd[f][r]);
        s[f][r] = p;
        lrow[r] += p;
      }
    // PV per kk-half: write Ps half (swizzled), read pf, tr-read V, 4 MFMAs
    {
      unsigned va = vtb + (unsigned)(buf << 13);
      i32x2 t0, t1, t2, t3, t4, t5, t6, t7;
      bf16x8 pf;
#define TRRD(d_, o_) asm volatile("ds_read_b64_tr_b16 %0, %1 offset:" o_ : "=v"(d_) : "v"(va))
      // ---- kk = 0: P cols 0..31 (f=0,1)
#pragma unroll
      for (int f = 0; f < 2; ++f)
#pragma unroll
        for (int r = 0; r < 4; ++r) {
          int row = w * 16 + lg * 4 + r;
          Ps[row][(f * 16 + lr) ^ (lg << 3)] = f2b(s[f][r]);
        }
      pf = *(const bf16x8*)&Ps[w * 16 + lr][(lg ^ ((lr >> 2) & 3)) * 8];
      TRRD(t0, "0");    TRRD(t1, "128");
      TRRD(t2, "2048"); TRRD(t3, "2176");
      TRRD(t4, "4096"); TRRD(t5, "4224");
      TRRD(t6, "6144"); TRRD(t7, "6272");
      asm volatile("s_waitcnt lgkmcnt(0)" ::: "memory");
      __builtin_amdgcn_sched_barrier(0);
      __builtin_amdgcn_s_setprio(1);
      oacc[0] = __builtin_amdgcn_mfma_f32_16x16x32_bf16(pf, cat64(t0, t1), oacc[0], 0, 0, 0);
      oacc[1] = __builtin_amdgcn_mfma_f32_16x16x32_bf16(pf, cat64(t2, t3), oacc[1], 0, 0, 0);
      oacc[2] = __builtin_amdgcn_mfma_f32_16x16x32_bf16(pf, cat64(t4, t5), oacc[2], 0, 0, 0);
      oacc[3] = __builtin_amdgcn_mfma_f32_16x16x32_bf16(pf, cat64(t6, t7), oacc[3], 0, 0, 0);
      __builtin_amdgcn_s_setprio(0);
      // ---- kk = 1: P cols 32..63 (f=2,3), same Ps slots (same-wave DS ordering)
#pragma unroll
      for (int f = 2; f < 4; ++f)
#pragma unroll
        for (int r = 0; r < 4; ++r) {
          int row = w * 16 + lg * 4 + r;
          Ps[row][((f - 2) * 16 + lr) ^ (lg << 3)] = f2b(s[f][r]);
        }
      pf = *(const bf16x8*)&Ps[w * 16 + lr][(lg ^ ((lr >> 2) & 3)) * 8];
      TRRD(t0, "1024"); TRRD(t1, "1152");
      TRRD(t2, "3072"); TRRD(t3, "3200");
      TRRD(t4, "5120"); TRRD(t5, "5248");
      TRRD(t6, "7168"); TRRD(t7, "7296");
      asm volatile("s_waitcnt lgkmcnt(0)" ::: "memory");
      __builtin_amdgcn_sched_barrier(0);
      __builtin_amdgcn_s_setprio(1);
      oacc[0] = __builtin_amdgcn_mfma_f32_16x16x32_bf16(pf, cat64(t0, t1), oacc[0], 0, 0, 0);
      oacc[1] = __builtin_amdgcn_mfma_f32_16x16x32_bf16(pf, cat64(t2, t3), oacc[1], 0, 0, 0);
      oacc[2] = __builtin_amdgcn_mfma_f32_16x16x32_bf16(pf, cat64(t4, t5), oacc[2], 0, 0, 0);
      oacc[3] = __builtin_amdgcn_mfma_f32_16x16x32_bf16(pf, cat64(t6, t7), oacc[3], 0, 0, 0);
      __builtin_amdgcn_s_setprio(0);
#undef TRRD
    }
    // next iteration's BD panel (direct loads; rk hot in L2)
    if (u < 31) {
      int pb, sb; coords(u + 1, pb, sb);
      panel_direct(pb, sb);
    }
    __syncthreads();   // staging of u+1 complete, all PV reads of buf done
    buf ^= 1;
  }
  // final row-sum reduce across the 16-lane group (once, not per iteration)
#pragma unroll
  for (int r = 0; r < 4; ++r)
#pragma unroll
    for (int msk = 1; msk <= 8; msk <<= 1) lrow[r] += __shfl_xor(lrow[r], msk);
#pragma unroll
  for (int df = 0; df < 4; ++df)
#pragma unroll
    for (int r = 0; r < 4; ++r) {
      int i = q0 + w * 16 + lg * 4 + r;
      av[((size_t)i * 4 + b) * 1024 + n * 64 + df * 16 + lr] = f2b(oacc[df][r] / lrow[r]);
    }
}

// ---------------- residual + LayerNorm ----------------
__global__ __launch_bounds__(256) void ln_kernel(const float* __restrict__ w, const float* __restrict__ ao,
                                                 const float* __restrict__ g, const float* __restrict__ bb,
                                                 float* __restrict__ out) {
  const int row = blockIdx.x;
  const int t = threadIdx.x;
  const float4 wv = ((const float4*)(w + (size_t)row * 1024))[t];
  const float4 av = ((const float4*)(ao + (size_t)row * 1024))[t];
  float x0 = wv.x + av.x, x1 = wv.y + av.y, x2 = wv.z + av.z, x3 = wv.w + av.w;
  float s1 = x0 + x1 + x2 + x3;
  float s2 = x0 * x0 + x1 * x1 + x2 * x2 + x3 * x3;
#pragma unroll
  for (int m = 1; m <= 32; m <<= 1) { s1 += __shfl_xor(s1, m); s2 += __shfl_xor(s2, m); }
  __shared__ float red[8];
  const int lane = t & 63, wv2 = t >> 6;
  if (lane == 0) { red[wv2] = s1; red[4 + wv2] = s2; }
  __syncthreads();
  s1 = red[0] + red[1] + red[2] + red[3];
  s2 = red[4] + red[5] + red[6] + red[7];
  const float mu = s1 * (1.f / 1024.f);
  const float var = s2 * (1.f / 1024.f) - mu * mu;
  const float rr = rsqrtf(var + 1e-5f);
  const float4 gv = ((const float4*)g)[t];
  const float4 bv = ((const float4*)bb)[t];
  float4 o;
  o.x = (x0 - mu) * rr * gv.x + bv.x;
  o.y = (x1 - mu) * rr * gv.y + bv.y;
  o.z = (x2 - mu) * rr * gv.z + bv.z;
  o.w = (x3 - mu) * rr * gv.w + bv.w;
  ((float4*)(out + (size_t)row * 1024))[t] = o;
}

extern "C" void kernel_launch(void* const* d_in, const int* in_sizes, int n_in,
                              void* d_out, int out_size, void* d_ws, size_t ws_size,
                              hipStream_t stream) {
  const float* w    = (const float*)d_in[0];
  const float* r    = (const float*)d_in[1];
  const float* qkvw = (const float*)d_in[2];
  const float* rnw  = (const float*)d_in[3];
  const float* ow   = (const float*)d_in[4];
  const float* rwb  = (const float*)d_in[5];
  const float* rrb  = (const float*)d_in[6];
  const float* lng  = (const float*)d_in[7];
  const float* lnb  = (const float*)d_in[8];
  float* out = (float*)d_out;

  char* ws = (char*)d_ws;
  size_t off = 0;
  auto alloc = [&](size_t bytes) -> char* {
    char* p = ws + off; off += (bytes + 255) & ~((size_t)255); return p;
  };
  bf16*  wb  = (bf16*)alloc((size_t)8192 * 1024 * 2);
  bf16*  qb  = (bf16*)alloc((size_t)3072 * 1024 * 2);
  bf16*  rb  = (bf16*)alloc((size_t)2048 * 1024 * 2);
  bf16*  rnb = (bf16*)alloc((size_t)1024 * 1024 * 2);
  bf16*  owb = (bf16*)alloc((size_t)1024 * 1024 * 2);
  bf16*  wh  = (bf16*)alloc((size_t)8192 * 3072 * 2);
  bf16*  rkb = (bf16*)alloc((size_t)2048 * 1024 * 2);
  bf16*  avb = (bf16*)alloc((size_t)8192 * 1024 * 2);
  float* ao  = (float*)alloc((size_t)8192 * 1024 * 4);

  auto cvt = [&](const float* in, bf16* o, size_t nelem) {
    int n4 = (int)(nelem / 4);
    cvt_kernel<<<dim3((n4 + 255) / 256), dim3(256), 0, stream>>>(in, o, n4);
  };
  cvt(w, wb, (size_t)8192 * 1024);
  cvt(qkvw, qb, (size_t)3072 * 1024);
  cvt(r, rb, (size_t)2048 * 1024);
  cvt(rnw, rnb, (size_t)1024 * 1024);
  cvt(ow, owb, (size_t)1024 * 1024);

  gemm_bt<1><<<dim3(3072 / 128, 8192 / 128), dim3(256), 0, stream>>>(wb, qb, wh, 8192, 3072, 1024);
  gemm_bt<1><<<dim3(1024 / 128, 2048 / 128), dim3(256), 0, stream>>>(rb, rnb, rkb, 2048, 1024, 1024);

  flash_kernel<<<dim3(2048), dim3(256), 0, stream>>>(wh, rkb, rwb, rrb, avb);

  gemm_bt<0><<<dim3(1024 / 128, 8192 / 128), dim3(256), 0, stream>>>(avb, owb, ao, 8192, 1024, 1024);
  ln_kernel<<<dim3(8192), dim3(256), 0, stream>>>(w, ao, lng, lnb, out);
}